// Round 4
// baseline (210.365 us; speedup 1.0000x reference)
//
#include <hip/hip_runtime.h>
#include <hip/hip_bf16.h>

#define N_ROWS 4096
#define DIM 512
#define TWO_N 8192
#define NTILE 64                 // 8192 / 128
#define NTRI  (NTILE * (NTILE + 1) / 2)   // 2080 upper-tri blocks

typedef __bf16 bf16x8 __attribute__((ext_vector_type(8)));
typedef float  f32x4  __attribute__((ext_vector_type(4)));

// ---------------------------------------------------------------------------
// round-to-nearest-even float -> bf16 bits
__device__ inline unsigned short f2bf(float f) {
    unsigned int u = __float_as_uint(f);
    u += 0x7fffu + ((u >> 16) & 1u);
    return (unsigned short)(u >> 16);
}

// ---------------------------------------------------------------------------
// Kernel 1: normalize rows of emb_i / emb_j, emit bf16 z [2N][D], pos[N],
// zero denom[2N] and out[0]. One block (256 thr) per row pair.
__global__ void normalize_kernel(const float* __restrict__ ei,
                                 const float* __restrict__ ej,
                                 unsigned short* __restrict__ zb,
                                 float* __restrict__ pos,
                                 float* __restrict__ denom,
                                 float* __restrict__ out) {
    int r = blockIdx.x;          // 0..4095
    int t = threadIdx.x;         // 0..255, each handles 2 dims via float2
    const float2 vi = ((const float2*)(ei + (size_t)r * DIM))[t];
    const float2 vj = ((const float2*)(ej + (size_t)r * DIM))[t];
    float si  = vi.x * vi.x + vi.y * vi.y;
    float sj  = vj.x * vj.x + vj.y * vj.y;
    float sij = vi.x * vj.x + vi.y * vj.y;

    for (int o = 32; o; o >>= 1) {
        si  += __shfl_down(si, o);
        sj  += __shfl_down(sj, o);
        sij += __shfl_down(sij, o);
    }
    __shared__ float red[3][4];
    int wave = t >> 6, lane = t & 63;
    if (lane == 0) { red[0][wave] = si; red[1][wave] = sj; red[2][wave] = sij; }
    __syncthreads();
    si  = red[0][0] + red[0][1] + red[0][2] + red[0][3];
    sj  = red[1][0] + red[1][1] + red[1][2] + red[1][3];
    sij = red[2][0] + red[2][1] + red[2][2] + red[2][3];

    float rni = 1.0f / fmaxf(sqrtf(si), 1e-12f);
    float rnj = 1.0f / fmaxf(sqrtf(sj), 1e-12f);
    if (t == 0) {
        pos[r] = sij * rni * rnj;
        denom[r] = 0.0f;
        denom[r + N_ROWS] = 0.0f;
        if (r == 0) out[0] = 0.0f;   // accumulated by loss_kernel (stream-ordered)
    }
    ushort2 zi2 = make_ushort2(f2bf(vi.x * rni), f2bf(vi.y * rni));
    ushort2 zj2 = make_ushort2(f2bf(vj.x * rnj), f2bf(vj.y * rnj));
    ((ushort2*)(zb + (size_t)r * DIM))[t] = zi2;
    ((ushort2*)(zb + (size_t)(r + N_ROWS) * DIM))[t] = zj2;
}

// ---------------------------------------------------------------------------
// Kernel 2: upper-triangular 128x128-tile bf16 MFMA GEMM of z·zT with
// NO LDS staging: MFMA fragments (16B contiguous) load straight from
// global (L1/L2-resident) into registers via global_load_dwordx4 with
// literal k-offsets. No barriers in the K-loop -> compiler software-
// pipelines loads across iterations (escapes the vmcnt(0) barrier drain).
// Per-iter block working set = 16 KB -> L1 serves sibling-wave redundancy.
// Block (by<=bx) adds exp(2*sim) row-sums to denom[rb..] and (off-diag)
// col-sums to denom[cb..]; diag blocks mask grow==gcol.
__global__ __launch_bounds__(256) void gemm_exp_kernel(
        const unsigned short* __restrict__ zb,
        float* __restrict__ denom) {
    // ---- linear index -> (by, bx), by <= bx, row-major over by ----
    const int t = blockIdx.x;
    int by = (int)(0.5f * (2.0f * NTILE + 1.0f -
              sqrtf((2.0f * NTILE + 1.0f) * (2.0f * NTILE + 1.0f) - 8.0f * t)));
    while ((by + 1) * NTILE - ((by + 1) * by) / 2 <= t) ++by;
    while (by * NTILE - (by * (by - 1)) / 2 > t) --by;
    const int bx = by + (t - (by * NTILE - (by * (by - 1)) / 2));

    const int rb = by * 128;             // row tile base
    const int cb = bx * 128;             // col tile base
    const bool diag = (rb == cb);

    const int tid  = threadIdx.x;
    const int wave = tid >> 6;
    const int lane = tid & 63;
    const int quad = lane >> 4;          // 0..3
    const int m    = lane & 15;          // 0..15
    const int wm   = (wave >> 1) * 64;   // wave row offset in tile
    const int wn   = (wave & 1) * 64;    // wave col offset in tile

    // Hoisted fragment base pointers: row (wm+i*16+m), k-offset quad*8.
    // Per-chunk advance is c*32 elements = c*64 bytes -> literal offsets.
    const unsigned short* pa[4];
    const unsigned short* pb[4];
    #pragma unroll
    for (int i = 0; i < 4; ++i) {
        pa[i] = zb + (size_t)(rb + wm + i * 16 + m) * DIM + quad * 8;
        pb[i] = zb + (size_t)(cb + wn + i * 16 + m) * DIM + quad * 8;
    }

    f32x4 acc[4][4];
    #pragma unroll
    for (int i = 0; i < 4; ++i)
        #pragma unroll
        for (int j = 0; j < 4; ++j)
            #pragma unroll
            for (int r = 0; r < 4; ++r) acc[i][j][r] = 0.0f;

    bf16x8 af[2][4], bf_[2][4];
    #pragma unroll
    for (int i = 0; i < 4; ++i) {
        af[0][i]  = *(const bf16x8*)(pa[i]);
        bf_[0][i] = *(const bf16x8*)(pb[i]);
    }

    #pragma unroll
    for (int c = 0; c < 16; ++c) {       // 16 chunks of K=32
        const int cur = c & 1, nxt = cur ^ 1;
        if (c < 15) {
            #pragma unroll
            for (int i = 0; i < 4; ++i) {
                af[nxt][i]  = *(const bf16x8*)(pa[i] + (c + 1) * 32);
                bf_[nxt][i] = *(const bf16x8*)(pb[i] + (c + 1) * 32);
            }
        }
        #pragma unroll
        for (int i = 0; i < 4; ++i)
            #pragma unroll
            for (int j = 0; j < 4; ++j)
                acc[i][j] = __builtin_amdgcn_mfma_f32_16x16x32_bf16(
                    af[cur][i], bf_[cur][j], acc[i][j], 0, 0, 0);
    }

    // ---- epilogue: exp(2*sim), mask diag, row sums (+ col sums off-diag) ----
    __shared__ float rs[128];
    __shared__ float cs[128];
    if (tid < 128) { rs[tid] = 0.0f; cs[tid] = 0.0f; }
    __syncthreads();

    float colsum[4] = {0.0f, 0.0f, 0.0f, 0.0f};
    #pragma unroll
    for (int i = 0; i < 4; ++i) {
        #pragma unroll
        for (int r = 0; r < 4; ++r) {
            int lrow = wm + i * 16 + quad * 4 + r;    // local row 0..127
            int grow = rb + lrow;
            float s = 0.0f;
            #pragma unroll
            for (int j = 0; j < 4; ++j) {
                int gcol = cb + wn + j * 16 + m;
                float v  = __expf(2.0f * acc[i][j][r]);
                v = (grow == gcol) ? 0.0f : v;
                s += v;
                colsum[j] += v;
            }
            // sum across the 16 lanes of this quad-row group (bits 0..3)
            s += __shfl_xor(s, 1);
            s += __shfl_xor(s, 2);
            s += __shfl_xor(s, 4);
            s += __shfl_xor(s, 8);
            if (m == 0) atomicAdd(&rs[lrow], s);
        }
    }
    if (!diag) {
        #pragma unroll
        for (int j = 0; j < 4; ++j) {
            float s = colsum[j];       // this wave's 64 rows, col wn+j*16+m
            s += __shfl_xor(s, 16);    // combine across quads (rows)
            s += __shfl_xor(s, 32);
            if (quad == 0) atomicAdd(&cs[wn + j * 16 + m], s);
        }
    }
    __syncthreads();
    if (tid < 128) {
        atomicAdd(&denom[rb + tid], rs[tid]);
        if (!diag) atomicAdd(&denom[cb + tid], cs[tid]);
    }
}

// ---------------------------------------------------------------------------
// Kernel 3: loss += sum_r [ log(denom[r]) - 2*pos[r % N] ] / 2N.
// 32 blocks x 256 threads, one row each; per-block reduce + one atomic.
__global__ void loss_kernel(const float* __restrict__ pos,
                            const float* __restrict__ denom,
                            float* __restrict__ out) {
    int r = blockIdx.x * 256 + threadIdx.x;   // 0..8191
    float s = __logf(denom[r]) - 2.0f * pos[r & (N_ROWS - 1)];
    for (int o = 32; o; o >>= 1) s += __shfl_down(s, o);
    __shared__ float red[4];
    int t = threadIdx.x;
    if ((t & 63) == 0) red[t >> 6] = s;
    __syncthreads();
    if (t == 0)
        atomicAdd(out, (red[0] + red[1] + red[2] + red[3]) / (float)TWO_N);
}

// ---------------------------------------------------------------------------
extern "C" void kernel_launch(void* const* d_in, const int* in_sizes, int n_in,
                              void* d_out, int out_size, void* d_ws, size_t ws_size,
                              hipStream_t stream) {
    const float* ei = (const float*)d_in[0];
    const float* ej = (const float*)d_in[1];

    // ws layout: zb (bf16, 2N*D = 8 MB) | pos (N f32) | denom (2N f32)
    unsigned short* zb  = (unsigned short*)d_ws;
    float* pos   = (float*)((char*)d_ws + (size_t)TWO_N * DIM * sizeof(unsigned short));
    float* denom = pos + N_ROWS;
    float* out   = (float*)d_out;

    normalize_kernel<<<N_ROWS, 256, 0, stream>>>(ei, ej, zb, pos, denom, out);
    gemm_exp_kernel<<<NTRI, 256, 0, stream>>>(zb, denom);
    loss_kernel<<<TWO_N / 256, 256, 0, stream>>>(pos, denom, out);
}

// Round 6
// 163.669 us; speedup vs baseline: 1.2853x; 1.2853x over previous
//
#include <hip/hip_runtime.h>
#include <hip/hip_bf16.h>

#define N_ROWS 4096
#define DIM 512
#define TWO_N 8192
#define NTILE 64                 // 8192 / 128
#define NTRI  (NTILE * (NTILE + 1) / 2)   // 2080 upper-tri blocks

typedef __bf16 bf16x8 __attribute__((ext_vector_type(8)));
typedef float  f32x4  __attribute__((ext_vector_type(4)));

// ---------------------------------------------------------------------------
// round-to-nearest-even float -> bf16 bits
__device__ inline unsigned short f2bf(float f) {
    unsigned int u = __float_as_uint(f);
    u += 0x7fffu + ((u >> 16) & 1u);
    return (unsigned short)(u >> 16);
}

// ---------------------------------------------------------------------------
// Blocked z layout: fragment element j of lane l=(quad*16+m) for
// (row-tile rt, k-tile kt) = z[rt*16+m][kt*32+quad*8+j], stored at
// zblk[((rt*16+kt)*64 + l)*8 + j]. A wave's MFMA fragment load is then
// base + lane*16 -> one fully-coalesced global_load_dwordx4 (no LDS).
//
// Kernel 1: normalize rows of emb_i / emb_j, emit blocked bf16 z, pos[N],
// zero denom[2N] and out[0]. One block (256 thr) per row pair.
__global__ void normalize_kernel(const float* __restrict__ ei,
                                 const float* __restrict__ ej,
                                 unsigned short* __restrict__ zblk,
                                 float* __restrict__ pos,
                                 float* __restrict__ denom,
                                 float* __restrict__ out) {
    int r = blockIdx.x;          // 0..4095
    int t = threadIdx.x;         // 0..255, each handles 2 dims via float2
    const float2 vi = ((const float2*)(ei + (size_t)r * DIM))[t];
    const float2 vj = ((const float2*)(ej + (size_t)r * DIM))[t];
    float si  = vi.x * vi.x + vi.y * vi.y;
    float sj  = vj.x * vj.x + vj.y * vj.y;
    float sij = vi.x * vj.x + vi.y * vj.y;

    for (int o = 32; o; o >>= 1) {
        si  += __shfl_down(si, o);
        sj  += __shfl_down(sj, o);
        sij += __shfl_down(sij, o);
    }
    __shared__ float red[3][4];
    int wave = t >> 6, lane = t & 63;
    if (lane == 0) { red[0][wave] = si; red[1][wave] = sj; red[2][wave] = sij; }
    __syncthreads();
    si  = red[0][0] + red[0][1] + red[0][2] + red[0][3];
    sj  = red[1][0] + red[1][1] + red[1][2] + red[1][3];
    sij = red[2][0] + red[2][1] + red[2][2] + red[2][3];

    float rni = 1.0f / fmaxf(sqrtf(si), 1e-12f);
    float rnj = 1.0f / fmaxf(sqrtf(sj), 1e-12f);
    if (t == 0) {
        pos[r] = sij * rni * rnj;
        denom[r] = 0.0f;
        denom[r + N_ROWS] = 0.0f;
        if (r == 0) out[0] = 0.0f;   // accumulated by loss_kernel (stream-ordered)
    }
    // blocked-layout write: this thread owns elements k0=2t, 2t+1 of the row
    int kt   = t >> 4;             // (2t)>>5
    int quad = (t >> 2) & 3;       // ((2t)>>3)&3
    int j    = (t & 3) * 2;        // (2t)&7
    int m    = r & 15;
    size_t off_i = ((size_t)((r >> 4) * 16 + kt) * 64 + quad * 16 + m) * 8 + j;
    size_t off_j = ((size_t)(((r + N_ROWS) >> 4) * 16 + kt) * 64 + quad * 16 + m) * 8 + j;
    ushort2 zi2 = make_ushort2(f2bf(vi.x * rni), f2bf(vi.y * rni));
    ushort2 zj2 = make_ushort2(f2bf(vj.x * rnj), f2bf(vj.y * rnj));
    *(ushort2*)(zblk + off_i) = zi2;
    *(ushort2*)(zblk + off_j) = zj2;
}

// ---------------------------------------------------------------------------
// Kernel 2: upper-triangular 128x128-tile bf16 MFMA GEMM of z·zT reading
// MFMA fragments DIRECTLY from the blocked layout (coalesced, L1/L2-
// resident, no LDS, no K-loop barriers -> compiler pipelines loads with
// fine-grained vmcnt across iterations; escapes the m97 barrier drain).
// Block (by<=bx) adds exp(2*sim) row-sums to denom[rb..] and (off-diag)
// col-sums to denom[cb..]; diag blocks mask grow==gcol.
__global__ __launch_bounds__(256) void gemm_exp_kernel(
        const unsigned short* __restrict__ zblk,
        float* __restrict__ denom) {
    // ---- linear index -> (by, bx), by <= bx, row-major over by ----
    const int t = blockIdx.x;
    int by = (int)(0.5f * (2.0f * NTILE + 1.0f -
              sqrtf((2.0f * NTILE + 1.0f) * (2.0f * NTILE + 1.0f) - 8.0f * t)));
    while ((by + 1) * NTILE - ((by + 1) * by) / 2 <= t) ++by;
    while (by * NTILE - (by * (by - 1)) / 2 > t) --by;
    const int bx = by + (t - (by * NTILE - (by * (by - 1)) / 2));

    const int rb = by * 128;             // row tile base
    const int cb = bx * 128;             // col tile base
    const bool diag = (rb == cb);

    const int tid  = threadIdx.x;
    const int wave = tid >> 6;
    const int lane = tid & 63;
    const int quad = lane >> 4;          // 0..3
    const int m    = lane & 15;          // 0..15
    const int wm   = (wave >> 1) * 64;   // wave row offset in tile
    const int wn   = (wave & 1) * 64;    // wave col offset in tile

    // Fragment base pointers: A row-tile (rb+wm)/16+i, B col-tile (cb+wn)/16+i.
    // k-tile advance = +512 elements (1 KB). Loads are base + lane*16.
    const unsigned short* pa[4];
    const unsigned short* pb[4];
    #pragma unroll
    for (int i = 0; i < 4; ++i) {
        pa[i] = zblk + ((size_t)((rb + wm) / 16 + i) * 16 * 64 + lane) * 8;
        pb[i] = zblk + ((size_t)((cb + wn) / 16 + i) * 16 * 64 + lane) * 8;
    }

    f32x4 acc[4][4];
    #pragma unroll
    for (int i = 0; i < 4; ++i)
        #pragma unroll
        for (int j = 0; j < 4; ++j)
            #pragma unroll
            for (int r = 0; r < 4; ++r) acc[i][j][r] = 0.0f;

    bf16x8 af[2][4], bf_[2][4];
    #pragma unroll
    for (int i = 0; i < 4; ++i) {
        af[0][i]  = *(const bf16x8*)(pa[i]);
        bf_[0][i] = *(const bf16x8*)(pb[i]);
    }

    #pragma unroll
    for (int c = 0; c < 16; ++c) {       // 16 k-tiles of K=32
        const int cur = c & 1, nxt = cur ^ 1;
        if (c < 15) {
            #pragma unroll
            for (int i = 0; i < 4; ++i) {
                af[nxt][i]  = *(const bf16x8*)(pa[i] + (c + 1) * 512);
                bf_[nxt][i] = *(const bf16x8*)(pb[i] + (c + 1) * 512);
            }
        }
        #pragma unroll
        for (int i = 0; i < 4; ++i)
            #pragma unroll
            for (int j = 0; j < 4; ++j)
                acc[i][j] = __builtin_amdgcn_mfma_f32_16x16x32_bf16(
                    af[cur][i], bf_[cur][j], acc[i][j], 0, 0, 0);
    }

    // ---- epilogue: exp(2*sim), mask diag, row sums (+ col sums off-diag) ----
    __shared__ float rs[128];
    __shared__ float cs[128];
    if (tid < 128) { rs[tid] = 0.0f; cs[tid] = 0.0f; }
    __syncthreads();

    float colsum[4] = {0.0f, 0.0f, 0.0f, 0.0f};
    #pragma unroll
    for (int i = 0; i < 4; ++i) {
        #pragma unroll
        for (int r = 0; r < 4; ++r) {
            int lrow = wm + i * 16 + quad * 4 + r;    // local row 0..127
            int grow = rb + lrow;
            float s = 0.0f;
            #pragma unroll
            for (int j = 0; j < 4; ++j) {
                int gcol = cb + wn + j * 16 + m;
                float v  = __expf(2.0f * acc[i][j][r]);
                v = (grow == gcol) ? 0.0f : v;
                s += v;
                colsum[j] += v;
            }
            // sum across the 16 lanes of this quad-row group (bits 0..3)
            s += __shfl_xor(s, 1);
            s += __shfl_xor(s, 2);
            s += __shfl_xor(s, 4);
            s += __shfl_xor(s, 8);
            if (m == 0) atomicAdd(&rs[lrow], s);
        }
    }
    if (!diag) {
        #pragma unroll
        for (int j = 0; j < 4; ++j) {
            float s = colsum[j];       // this wave's 64 rows, col wn+j*16+m
            s += __shfl_xor(s, 16);    // combine across quads (rows)
            s += __shfl_xor(s, 32);
            if (quad == 0) atomicAdd(&cs[wn + j * 16 + m], s);
        }
    }
    __syncthreads();
    if (tid < 128) {
        atomicAdd(&denom[rb + tid], rs[tid]);
        if (!diag) atomicAdd(&denom[cb + tid], cs[tid]);
    }
}

// ---------------------------------------------------------------------------
// Kernel 3: loss += sum_r [ log(denom[r]) - 2*pos[r % N] ] / 2N.
// 32 blocks x 256 threads, one row each; per-block reduce + one atomic.
__global__ void loss_kernel(const float* __restrict__ pos,
                            const float* __restrict__ denom,
                            float* __restrict__ out) {
    int r = blockIdx.x * 256 + threadIdx.x;   // 0..8191
    float s = __logf(denom[r]) - 2.0f * pos[r & (N_ROWS - 1)];
    for (int o = 32; o; o >>= 1) s += __shfl_down(s, o);
    __shared__ float red[4];
    int t = threadIdx.x;
    if ((t & 63) == 0) red[t >> 6] = s;
    __syncthreads();
    if (t == 0)
        atomicAdd(out, (red[0] + red[1] + red[2] + red[3]) / (float)TWO_N);
}

// ---------------------------------------------------------------------------
extern "C" void kernel_launch(void* const* d_in, const int* in_sizes, int n_in,
                              void* d_out, int out_size, void* d_ws, size_t ws_size,
                              hipStream_t stream) {
    const float* ei = (const float*)d_in[0];
    const float* ej = (const float*)d_in[1];

    // ws layout: zblk (bf16 blocked, 2N*D = 8 MB) | pos (N f32) | denom (2N f32)
    unsigned short* zblk = (unsigned short*)d_ws;
    float* pos   = (float*)((char*)d_ws + (size_t)TWO_N * DIM * sizeof(unsigned short));
    float* denom = pos + N_ROWS;
    float* out   = (float*)d_out;

    normalize_kernel<<<N_ROWS, 256, 0, stream>>>(ei, ej, zblk, pos, denom, out);
    gemm_exp_kernel<<<NTRI, 256, 0, stream>>>(zblk, denom);
    loss_kernel<<<TWO_N / 256, 256, 0, stream>>>(pos, denom, out);
}